// Round 6
// baseline (183.373 us; speedup 1.0000x reference)
//
#include <hip/hip_runtime.h>
#include <math.h>

// GAT aggregation: B=8,S=512,N=32,H=256,V=100001
// One wave per (b,s) position; lane holds 4 consecutive H-elements.
// KEY OPT (round 6): masked neighbors have softmax weight exp(-1e9-m) == +0
// exactly in fp32, so their rows are never loaded. Compact the ~17 surviving
// candidate indices (self + unmasked neighbors) via ballot into a per-wave
// LDS list, then run the online-softmax gather ring over only those.
// Gather traffic: 135 MB -> ~72 MB. Bit-exact vs reference.

constexpr int H  = 256;
constexpr int NN = 32;        // neighbors
constexpr int C  = NN + 1;    // max candidates (self + neighbors)
constexpr int PF = 8;         // prefetch ring depth (8 x float4 = 32 VGPRs)
constexpr float SLOPE = 0.2f;

__device__ __forceinline__ float wave_sum(float v) {
#pragma unroll
  for (int off = 32; off > 0; off >>= 1)
    v += __shfl_xor(v, off, 64);
  return v;
}

__global__ __launch_bounds__(256, 4) void gat_kernel(
    const int*   __restrict__ node_ids,   // [npos]
    const int*   __restrict__ neighs,     // [npos, NN]
    const int*   __restrict__ mask,       // [npos, NN]
    const float* __restrict__ emb,        // [V, H]
    const float* __restrict__ a_w,        // [2H]
    const float* __restrict__ a_b,        // [1]
    float*       __restrict__ out,        // [npos, H]
    int npos)
{
  __shared__ int slds[4][C + 7];          // compacted candidate ids, per wave

  const int wid  = (blockIdx.x * blockDim.x + threadIdx.x) >> 6;
  const int wv   = (threadIdx.x >> 6);    // wave within block
  const int lane = threadIdx.x & 63;
  if (wid >= npos) return;                // wave-uniform
  const int l4 = lane << 2;

  const float4 aw1 = *(const float4*)(a_w + l4);       // src half of a_w
  const float4 aw2 = *(const float4*)(a_w + H + l4);   // candidate half
  const float  ab  = a_b[0];

  // Lane-parallel: lane 0 = self (never masked), lanes 1..NN = neighbors.
  bool active = false;
  int  my_idx = 0;
  if (lane == 0) {
    my_idx = node_ids[wid];
    active = true;
  } else if (lane <= NN) {
    my_idx = neighs[wid * NN + lane - 1];
    active = (mask[wid * NN + lane - 1] == 0);   // masked -> weight 0 -> skip
  }

  // Compact surviving candidate indices into LDS (slot 0 = self).
  const unsigned long long bal = __ballot(active);
  const int K = __popcll(bal);                   // ~17 on average
  if (active) {
    const int rank = __popcll(bal & ((1ull << lane) - 1ull));
    slds[wv][rank] = my_idx;
  }
  // Producer and consumer are the same wave: HW LDS ordering + compiler
  // lgkmcnt waits make this safe without a barrier.

  const float4* __restrict__ embv = (const float4*)emb;  // row = H/4 float4
  auto row = [&](int k) -> float4 {
    const int ic = __builtin_amdgcn_readfirstlane(slds[wv][k]); // SGPR base
    return embv[(size_t)ic * (H / 4) + lane];
  };

  float4 buf[PF];
#pragma unroll
  for (int i = 0; i < PF; ++i)
    if (i < K) buf[i] = row(i);

  float  m = -1e30f, s = 0.f, zsrc = 0.f;
  float4 acc = {0.f, 0.f, 0.f, 0.f};

#pragma unroll
  for (int c = 0; c < C; ++c) {
    if (c >= K) break;                    // wave-uniform early exit
    const float4 cur = buf[c & (PF - 1)];
    if (c + PF < K) buf[c & (PF - 1)] = row(c + PF);

    float p = cur.x * aw2.x + cur.y * aw2.y + cur.z * aw2.z + cur.w * aw2.w;
    if (c == 0) {
      float ps = cur.x * aw1.x + cur.y * aw1.y + cur.z * aw1.z + cur.w * aw1.w;
      zsrc = wave_sum(ps);                // src·aw1, shared by every candidate
    }
    const float z = zsrc + wave_sum(p) + ab;
    const float a = (z > 0.f) ? z : SLOPE * z;    // LeakyReLU(0.2); no mask add
                                                   // (all survivors unmasked)
    // Online softmax update (wave-uniform values)
    const float mnew  = fmaxf(m, a);
    const float scale = __expf(m - mnew);
    const float pr    = __expf(a - mnew);
    s = s * scale + pr;
    acc.x = acc.x * scale + pr * cur.x;
    acc.y = acc.y * scale + pr * cur.y;
    acc.z = acc.z * scale + pr * cur.z;
    acc.w = acc.w * scale + pr * cur.w;
    m = mnew;
  }

  const float inv = 1.f / s;
  float4 o = {acc.x * inv, acc.y * inv, acc.z * inv, acc.w * inv};
  *(float4*)(out + (size_t)wid * H + l4) = o;
}

extern "C" void kernel_launch(void* const* d_in, const int* in_sizes, int n_in,
                              void* d_out, int out_size, void* d_ws, size_t ws_size,
                              hipStream_t stream) {
  const int*   node_ids = (const int*)d_in[0];
  const int*   neighs   = (const int*)d_in[1];
  const int*   mask     = (const int*)d_in[2];
  const float* emb      = (const float*)d_in[3];
  const float* a_w      = (const float*)d_in[4];
  const float* a_b      = (const float*)d_in[5];
  float*       out      = (float*)d_out;

  const int npos = in_sizes[0];           // B*S = 4096
  const int waves_per_block = 256 / 64;   // 4 positions per block
  const int grid = (npos + waves_per_block - 1) / waves_per_block;

  gat_kernel<<<grid, 256, 0, stream>>>(node_ids, neighs, mask, emb, a_w, a_b,
                                       out, npos);
}

// Round 7
// 158.790 us; speedup vs baseline: 1.1548x; 1.1548x over previous
//
#include <hip/hip_runtime.h>
#include <math.h>

// GAT aggregation: B=8,S=512,N=32,H=256,V=100001
// One wave per (b,s) position; lane holds 4 consecutive H-elements.
// Masked neighbors have softmax weight exp(-1e9-m) == +0 exactly in fp32,
// so their rows are never loaded (~17 of 33 survive). Round-7 fix vs round 6:
// the candidate loop is fully unrolled over all 33 slots with a wave-uniform
// SCALAR guard (s_cbranch) per slot -- no data-dependent break -- so the
// prefetch ring keeps compile-time indices and stays in VGPRs (round 6's
// rolled loop pushed it to scratch). Candidate list is compacted via ballot
// into LDS, read back ONCE (lane k = candidate k), then per-slot v_readlane
// (literal lane) gives an SGPR row base with no DS ops in the load path.

constexpr int H  = 256;
constexpr int NN = 32;        // neighbors
constexpr int C  = NN + 1;    // max candidates (self + neighbors)
constexpr int PF = 16;        // prefetch ring depth (16 x float4 = 64 VGPRs)
constexpr float SLOPE = 0.2f;

__device__ __forceinline__ float wave_sum(float v) {
#pragma unroll
  for (int off = 32; off > 0; off >>= 1)
    v += __shfl_xor(v, off, 64);
  return v;
}

__global__ __launch_bounds__(256, 4) void gat_kernel(
    const int*   __restrict__ node_ids,   // [npos]
    const int*   __restrict__ neighs,     // [npos, NN]
    const int*   __restrict__ mask,       // [npos, NN]
    const float* __restrict__ emb,        // [V, H]
    const float* __restrict__ a_w,        // [2H]
    const float* __restrict__ a_b,        // [1]
    float*       __restrict__ out,        // [npos, H]
    int npos)
{
  __shared__ int slds[4][64];             // compacted candidate ids, per wave

  const int wid  = (blockIdx.x * blockDim.x + threadIdx.x) >> 6;
  const int wv   = (threadIdx.x >> 6);    // wave within block
  const int lane = threadIdx.x & 63;
  if (wid >= npos) return;                // wave-uniform
  const int l4 = lane << 2;

  const float4 aw1 = *(const float4*)(a_w + l4);       // src half of a_w
  const float4 aw2 = *(const float4*)(a_w + H + l4);   // candidate half
  const float  ab  = a_b[0];

  // Lane-parallel: lane 0 = self (never masked), lanes 1..NN = neighbors.
  bool active = false;
  int  my_idx = 0;
  if (lane == 0) {
    my_idx = node_ids[wid];
    active = true;
  } else if (lane <= NN) {
    my_idx = neighs[wid * NN + lane - 1];
    active = (mask[wid * NN + lane - 1] == 0);   // masked -> weight 0 -> skip
  }

  // Compact surviving candidate ids into LDS (slot 0 = self), read back once.
  const unsigned long long bal = __ballot(active);
  const int K = __popcll(bal);                   // wave-uniform, ~17 avg
  if (active) {
    const int rank = (int)__popcll(bal & ((1ull << lane) - 1ull));
    slds[wv][rank] = my_idx;
  }
  // Same-wave LDS write->read: DS ops execute in order within a wave.
  const int cidx = slds[wv][lane];               // lane k = candidate k's id

  const float4* __restrict__ embv = (const float4*)emb;  // row = H/4 float4
  auto rowbase = [&](int c) -> const float4* {
    const int ic = __builtin_amdgcn_readlane(cidx, c);   // literal lane -> SGPR
    return embv + (size_t)ic * (H / 4);
  };

  float4 buf[PF];
#pragma unroll
  for (int i = 0; i < PF; ++i)
    if (i < K) buf[i] = rowbase(i)[lane];        // scalar guard, const index

  float  m = -1e30f, s = 0.f, zsrc = 0.f;
  float4 acc = {0.f, 0.f, 0.f, 0.f};

#pragma unroll
  for (int c = 0; c < C; ++c) {
    if (c < K) {                                 // wave-uniform scalar guard
      const float4 cur = buf[c & (PF - 1)];
      if (c + PF < K) buf[c & (PF - 1)] = rowbase(c + PF)[lane];

      float p = cur.x * aw2.x + cur.y * aw2.y + cur.z * aw2.z + cur.w * aw2.w;
      if (c == 0) {
        float ps = cur.x * aw1.x + cur.y * aw1.y + cur.z * aw1.z + cur.w * aw1.w;
        zsrc = wave_sum(ps);                     // src·aw1, shared by all c
      }
      const float z = zsrc + wave_sum(p) + ab;
      const float a = (z > 0.f) ? z : SLOPE * z; // LeakyReLU; survivors unmasked

      // Online softmax update (wave-uniform values)
      const float mnew  = fmaxf(m, a);
      const float scale = __expf(m - mnew);
      const float pr    = __expf(a - mnew);
      s = s * scale + pr;
      acc.x = acc.x * scale + pr * cur.x;
      acc.y = acc.y * scale + pr * cur.y;
      acc.z = acc.z * scale + pr * cur.z;
      acc.w = acc.w * scale + pr * cur.w;
      m = mnew;
    }
  }

  const float inv = 1.f / s;
  float4 o = {acc.x * inv, acc.y * inv, acc.z * inv, acc.w * inv};
  *(float4*)(out + (size_t)wid * H + l4) = o;
}

extern "C" void kernel_launch(void* const* d_in, const int* in_sizes, int n_in,
                              void* d_out, int out_size, void* d_ws, size_t ws_size,
                              hipStream_t stream) {
  const int*   node_ids = (const int*)d_in[0];
  const int*   neighs   = (const int*)d_in[1];
  const int*   mask     = (const int*)d_in[2];
  const float* emb      = (const float*)d_in[3];
  const float* a_w      = (const float*)d_in[4];
  const float* a_b      = (const float*)d_in[5];
  float*       out      = (float*)d_out;

  const int npos = in_sizes[0];           // B*S = 4096
  const int waves_per_block = 256 / 64;   // 4 positions per block
  const int grid = (npos + waves_per_block - 1) / waves_per_block;

  gat_kernel<<<grid, 256, 0, stream>>>(node_ids, neighs, mask, emb, a_w, a_b,
                                       out, npos);
}

// Round 8
// 152.054 us; speedup vs baseline: 1.2060x; 1.0443x over previous
//
#include <hip/hip_runtime.h>
#include <math.h>

// GAT aggregation: B=8,S=512,N=32,H=256,V=100001
// One BLOCK (4 waves) per position. Ledger through R7 shows the kernel is
// latency-bound (volume & compute changes flat; only occupancy moved it), so
// this round splits each position's ~17 surviving candidates (masked ones
// have softmax weight exactly +0 and are never loaded) across 4 waves:
//   - wave 0 compacts survivor ids via ballot into LDS
//   - wave w handles survivors {w, w+4, w+8, ...} (~4-5 each), rows loaded
//     upfront (independent, all in flight), partial online softmax (m,s,acc)
//   - block merges partials through LDS; wave 0 stores the 1 KB output row
// 4x the waves (16 work-waves/SIMD), ~4x shorter serial chain per wave.

constexpr int H    = 256;
constexpr int NN   = 32;                  // neighbors
constexpr int C    = NN + 1;              // max candidates (self + neighbors)
constexpr int WPB  = 4;                   // waves per block (= per position)
constexpr int JMAX = (C + WPB - 1) / WPB; // max candidates per wave = 9
constexpr float SLOPE = 0.2f;

__device__ __forceinline__ float wave_sum(float v) {
#pragma unroll
  for (int off = 32; off > 0; off >>= 1)
    v += __shfl_xor(v, off, 64);
  return v;
}

__global__ __launch_bounds__(256, 5) void gat_kernel(
    const int*   __restrict__ node_ids,   // [npos]
    const int*   __restrict__ neighs,     // [npos, NN]
    const int*   __restrict__ mask,       // [npos, NN]
    const float* __restrict__ emb,        // [V, H]
    const float* __restrict__ a_w,        // [2H]
    const float* __restrict__ a_b,        // [1]
    float*       __restrict__ out)        // [npos, H]
{
  __shared__ int    sidx[64];             // compacted survivor ids
  __shared__ int    sKs;                  // survivor count
  __shared__ float  smx[WPB], ssum[WPB];  // per-wave partial m, s
  __shared__ float4 sacc[WPB][64];        // per-wave partial acc (1 KB each)

  const int pos  = blockIdx.x;
  const int wv   = threadIdx.x >> 6;
  const int lane = threadIdx.x & 63;
  const int l4   = lane << 2;

  // ---- wave 0: load indices/mask, compact survivors (self never masked) ----
  if (wv == 0) {
    bool active = false;
    int  my     = 0;
    if (lane == 0) {
      my = node_ids[pos];
      active = true;
    } else if (lane <= NN) {
      my     = neighs[pos * NN + lane - 1];
      active = (mask[pos * NN + lane - 1] == 0);  // masked -> weight +0 -> skip
    }
    const unsigned long long bal = __ballot(active);
    if (active)
      sidx[(int)__popcll(bal & ((1ull << lane) - 1ull))] = my;
    if (lane == 0) sKs = (int)__popcll(bal);
  }
  __syncthreads();

  const int K    = __builtin_amdgcn_readfirstlane(sKs);   // SGPR, >= 1
  const int cidx = sidx[lane];                            // lane k = survivor k
  const int swv  = __builtin_amdgcn_readfirstlane(wv);    // SGPR wave id

  const float4 aw1 = *(const float4*)(a_w + l4);          // src half of a_w
  const float4 aw2 = *(const float4*)(a_w + H + l4);      // candidate half
  const float  ab  = a_b[0];
  const float4* __restrict__ embv = (const float4*)emb;   // row = H/4 float4

  // Self row (survivor 0) -> zsrc, needed by every wave.
  const int    iself = __builtin_amdgcn_readlane(cidx, 0);
  const float4 es    = embv[(size_t)iself * (H / 4) + lane];

  // Load this wave's candidate rows upfront (independent, all in flight).
  float4 buf[JMAX];
#pragma unroll
  for (int j = 0; j < JMAX; ++j) {
    const int c = swv + WPB * j;
    if (c < K) {                                          // scalar guard
      const int ic = __builtin_amdgcn_readlane(cidx, c);  // SGPR row index
      buf[j] = embv[(size_t)ic * (H / 4) + lane];
    }
  }

  const float zsrc = wave_sum(es.x * aw1.x + es.y * aw1.y +
                              es.z * aw1.z + es.w * aw1.w);

  // Partial online softmax over this wave's candidates.
  float  m = -1e30f, s = 0.f;
  float4 acc = {0.f, 0.f, 0.f, 0.f};
#pragma unroll
  for (int j = 0; j < JMAX; ++j) {
    const int c = swv + WPB * j;
    if (c < K) {
      const float4 cur = buf[j];
      const float  p   = wave_sum(cur.x * aw2.x + cur.y * aw2.y +
                                  cur.z * aw2.z + cur.w * aw2.w);
      const float z = zsrc + p + ab;
      const float a = (z > 0.f) ? z : SLOPE * z;          // LeakyReLU(0.2)
      const float mnew  = fmaxf(m, a);
      const float scale = __expf(m - mnew);
      const float pr    = __expf(a - mnew);
      s = s * scale + pr;
      acc.x = acc.x * scale + pr * cur.x;
      acc.y = acc.y * scale + pr * cur.y;
      acc.z = acc.z * scale + pr * cur.z;
      acc.w = acc.w * scale + pr * cur.w;
      m = mnew;
    }
  }

  // ---- block merge of the 4 partials ----
  sacc[wv][lane] = acc;
  if (lane == 0) { smx[wv] = m; ssum[wv] = s; }
  __syncthreads();

  if (wv == 0) {
    const float M = fmaxf(fmaxf(smx[0], smx[1]), fmaxf(smx[2], smx[3]));
    float  S = 0.f;
    float4 o = {0.f, 0.f, 0.f, 0.f};
#pragma unroll
    for (int w = 0; w < WPB; ++w) {
      const float f = __expf(smx[w] - M);   // empty wave: exp(-1e30-M) = +0
      S += ssum[w] * f;
      const float4 a = sacc[w][lane];
      o.x += f * a.x; o.y += f * a.y; o.z += f * a.z; o.w += f * a.w;
    }
    const float inv = 1.f / S;
    o.x *= inv; o.y *= inv; o.z *= inv; o.w *= inv;
    *(float4*)(out + (size_t)pos * H + l4) = o;
  }
}

extern "C" void kernel_launch(void* const* d_in, const int* in_sizes, int n_in,
                              void* d_out, int out_size, void* d_ws, size_t ws_size,
                              hipStream_t stream) {
  const int*   node_ids = (const int*)d_in[0];
  const int*   neighs   = (const int*)d_in[1];
  const int*   mask     = (const int*)d_in[2];
  const float* emb      = (const float*)d_in[3];
  const float* a_w      = (const float*)d_in[4];
  const float* a_b      = (const float*)d_in[5];
  float*       out      = (float*)d_out;

  const int npos = in_sizes[0];           // B*S = 4096
  gat_kernel<<<npos, 256, 0, stream>>>(node_ids, neighs, mask, emb, a_w, a_b,
                                       out);
}